// Round 1
// 1674.753 us; speedup vs baseline: 1.0101x; 1.0101x over previous
//
#include <hip/hip_runtime.h>

// ChainLoss (pychain leaky-HMM forward) on MI355X — round 10.
// Round-9 counters: HBM 8.6%, VALU 16.7%, MFMA 0 -> latency/sync bound.
// Per-step (~7160cy) decomposition: LDS gather ~2500cy, sync chain
// (drain+B2+flag+poll+B3+consume-load) ~2700-3200cy, rest ~1000-1500cy.
// THIS ROUND: self-validating publishes — the flag/drain/poll protocol is
// removed entirely. Alpha parts are strictly positive, so the SIGN BIT is a
// free freshness tag: publisher stores +aa / -aa by ((t>>1)&1) into the
// existing double buffer (par = t&1). Consecutive occupants of a slot
// alternate tags; t vs t+4 aliasing is impossible (publish(t+4) happens-after
// every block completed consume(t), by the consume->publish chain). Consumers
// spin on their OWN float2 until both lanes carry the expected sign, then
// fabsf recovers exact bits (same values, same reduce order in all 5 blocks
// -> bit-identical scale -> determinism kept, absmax 0.0).
// Removed per step: per-wave s_waitcnt vmcnt(0) drain, B2, flag store, the
// vector poll, B3. The consume load (issued BEFORE w-precompute so its LLC
// round trip overlaps ~725cy of LDS work) now IS the poll.
// First-ever-run workspace garbage: init_parts fills parts with -1.0
// (wrong tag for t=0/1); idempotent across iterations; replaces zero_flags.
// Retained (proven): G=5 state-split, 160 den + 32 num blocks, w-precompute
// in the wait window, obs wave-specialization with double buffer.
// Spill canary: WRITE_SIZE ~128 MB.

#define LEAKY 0.1f
#define AGENT __HIP_MEMORY_SCOPE_AGENT

constexpr int B = 32, T = 500, P = 3000;
constexpr int S_DEN = 2000;
constexpr int S_NUM = 100, E_NUM = 400;
constexpr int NTH = 1024;
constexpr int NWAVE = NTH / 64;
constexpr int G_DEN = 5;              // state-split factor
constexpr int SB = S_DEN / G_DEN;     // 400 states per den block
constexpr int KE = 20;                // incoming edges per state
constexpr int EPT = KE / 2;           // 10 edges per gather thread
constexpr int OBS_T0 = 800;           // threads >= OBS_T0 build obs
constexpr int OBS_N = NTH - OBS_T0;   // 224 obs threads
constexpr int OBS_IT = (P + OBS_N - 1) / OBS_N;  // 14
constexpr int KE_NUM = 4;
constexpr int NDEN_BLK = B * G_DEN;   // 160

// ws float layout:
//   [0,64)      per-seq logprob slots (32 den, 32 num)
//   [64,1088)   (unused; was flags in round 9)
//   [4096,..)   parts: seq b at 4096 + b*4096, slot par*2048 + state j
//               value = ((t>>1)&1) ? -alpha : +alpha  (sign = freshness tag)

__device__ __forceinline__ float clampexp(float x) {
  return __expf(fminf(fmaxf(x, -30.f), 30.f));
}
__device__ __forceinline__ void st_f32(float* p, float v) {
  __hip_atomic_store(p, v, __ATOMIC_RELAXED, AGENT);
}
__device__ __forceinline__ unsigned long long ld_u64(const float* p) {
  return __hip_atomic_load((const unsigned long long*)p, __ATOMIC_RELAXED,
                           AGENT);
}

// full-block reduce; caller guarantees wpart free (barrier since last use)
__device__ __forceinline__ float reduce_1024(float v, float* wpart) {
#pragma unroll
  for (int off = 32; off; off >>= 1) v += __shfl_xor(v, off, 64);
  if ((threadIdx.x & 63) == 0) wpart[threadIdx.x >> 6] = v;
  __syncthreads();
  float s = 0.f;
#pragma unroll
  for (int w = 0; w < NWAVE; ++w) s += wpart[w];
  return s;
}

__device__ void run_den(const float* __restrict__ xb,
                        const int* __restrict__ ef_g,
                        const int* __restrict__ ep_g,
                        const float* __restrict__ epr_g,
                        const float* __restrict__ einit,
                        const float* __restrict__ efinal, int b, int g,
                        float* __restrict__ outs, float* __restrict__ parts_b,
                        float* obsA, float* obsB, float* cur, float* ini_s,
                        float* tmp, float* wpart) {
  const int tid = threadIdx.x;
  const bool gat = tid < 2 * SB;          // 800 gather threads
  const bool own = tid < SB;              // owns state j
  const bool cons = tid < S_DEN / 2;      // consumes a float2 of parts
  const int jloc = own ? tid : (gat ? tid - SB : 0);
  const int khalf = (tid >= SB && gat) ? 1 : 0;
  const int j = g * SB + jloc;

  // init ini_s, cur, leakfac
  float lsum = 0.f;
  if (tid < S_DEN / 2) {
    const float2 iv = ((const float2*)einit)[tid];
    ((float2*)ini_s)[tid] = iv;
    ((float2*)cur)[tid] = iv;
    lsum = iv.x + iv.y;
  }
  __syncthreads();
  const float leakfac = 1.f + LEAKY * reduce_1024(lsum, wpart);

  // cache 10 edges of state j (half khalf): packed from|pdf<<16 + prob
  int efep[EPT];
  float epr[EPT], w[EPT];
  if (gat) {
#pragma unroll
    for (int k = 0; k < EPT; ++k) {
      const int e = j + (khalf * EPT + k) * S_DEN;
      efep[k] = ef_g[e] | (ep_g[e] << 16);
      epr[k] = epr_g[e];
    }
  }

  // obs(t=0) by everyone (coalesced); obs-threads prefetch x row 1
  obsA[tid] = clampexp(xb[tid]);
  obsA[tid + 1024] = clampexp(xb[tid + 1024]);
  if (tid + 2048 < P) obsA[tid + 2048] = clampexp(xb[tid + 2048]);
  float xr[OBS_IT];
  if (tid >= OBS_T0) {
    const float* r = xb + P;
#pragma unroll
    for (int i = 0; i < OBS_IT; ++i) {
      const int p = tid - OBS_T0 + OBS_N * i;
      xr[i] = (p < P) ? r[p] : 0.f;
    }
  }
  __syncthreads();
  // w for t=0 from obsA
  if (gat) {
#pragma unroll
    for (int k = 0; k < EPT; ++k) w[k] = epr[k] * obsA[efep[k] >> 16];
  }

  float logz = 0.f;
  for (int t = 0; t < T; ++t) {
    const int par = t & 1;
    float* obs_n = par ? obsA : obsB;  // obs(t+1) buffer
    // phase G: gather threads do 10 fused reads; obs threads build obs_n
    float a = 0.f;
    if (gat) {
#pragma unroll
      for (int k = 0; k < EPT; ++k) a += cur[efep[k] & 0xffff] * w[k];
      if (!own) tmp[jloc] = a;  // second half stages its partial
    } else if (tid >= OBS_T0) {
      float nxr[OBS_IT];
      const int tn = (t + 2 < T) ? t + 2 : T - 1;
      const float* r = xb + (size_t)tn * P;
#pragma unroll
      for (int i = 0; i < OBS_IT; ++i) {   // issue x[t+2] loads early
        const int p = tid - OBS_T0 + OBS_N * i;
        nxr[i] = (p < P) ? r[p] : 0.f;
      }
      if (t + 1 < T) {
#pragma unroll
        for (int i = 0; i < OBS_IT; ++i) {
          const int p = tid - OBS_T0 + OBS_N * i;
          if (p < P) obs_n[p] = clampexp(xr[i]);
        }
      }
#pragma unroll
      for (int i = 0; i < OBS_IT; ++i) xr[i] = nxr[i];
    }
    __syncthreads();  // B1: tmp + obs_n ready (gather LDS reads for t done)
    // owners combine + publish own unnorm alpha, sign-tagged by (t>>1)&1.
    // No drain, no flag: each datum self-announces via its sign bit.
    const unsigned tag = ((unsigned)t >> 1) & 1u;
    if (own) {
      const float aa = a + tmp[tid];
      st_f32(parts_b + par * 2048 + j, tag ? -aa : aa);
    }
    // fire the consume load NOW — its LLC round trip overlaps w-precompute
    const float* myp = parts_b + par * 2048 + 2 * tid;
    unsigned long long u = 0;
    if (cons) u = ld_u64(myp);
    // w-precompute for t+1 — fills the wait window (obs_n ready since B1)
    if (gat && t + 1 < T) {
#pragma unroll
      for (int k = 0; k < EPT; ++k) w[k] = epr[k] * obs_n[efep[k] >> 16];
    }
    // per-thread spin: both lanes of own float2 must carry tag's sign
    if (cons) {
      while ((((unsigned)(u >> 31) & 1u) != tag) ||
             (((unsigned)(u >> 63) & 1u) != tag)) {
        __builtin_amdgcn_s_sleep(1);
        u = ld_u64(myp);
      }
    }
    union { unsigned long long q; float2 f; } cc;
    cc.q = u;
    const float2 v2 = make_float2(fabsf(cc.f.x), fabsf(cc.f.y));  // exact bits
    // tot via deterministic block reduce: same data, same order in all 5
    // blocks -> bit-identical scale everywhere (reduce's barrier = converge)
    const float tot = reduce_1024(v2.x + v2.y, wpart);
    const float scale = tot * leakfac;  // normalization choice telescopes out
    const float inv = 1.f / scale, lt = LEAKY * tot;
    if (cons) {
      const float2 i2 = ((const float2*)ini_s)[tid];
      ((float2*)cur)[tid] = make_float2(fmaf(lt, i2.x, v2.x) * inv,
                                        fmaf(lt, i2.y, v2.y) * inv);
    }
    logz += __logf(scale);
    __syncthreads();  // B4: cur ready for step t+1 (also fences wpart reuse)
  }

  float fv = 0.f;
  if (tid < S_DEN / 2) {
    const float2 f2 = ((const float2*)efinal)[tid];
    const float2 c2 = ((float2*)cur)[tid];
    fv = c2.x * f2.x + c2.y * f2.y;
  }
  const float fin = reduce_1024(fv, wpart);
  if (tid == 0 && g == 0) outs[b] = logz + __logf(fin);
}

__device__ void run_num(const float* __restrict__ xb, const int* __restrict__ ef,
                        const int* __restrict__ ep, const float* __restrict__ epr,
                        const float* __restrict__ einit,
                        const float* __restrict__ efinal,
                        float* __restrict__ out_slot, float* __restrict__ obs,
                        float* __restrict__ cur, float* __restrict__ wpart) {
  const int tid = threadIdx.x;
  const bool act = tid < S_NUM / 2;
  const int j = 2 * tid;
  float2 ini = make_float2(0.f, 0.f), fin2 = make_float2(0.f, 0.f);
  if (act) {
    ini = ((const float2*)einit)[tid];
    fin2 = ((const float2*)efinal)[tid];
  }
  __syncthreads();
  const float leakfac =
      1.f + LEAKY * reduce_1024(act ? ini.x + ini.y : 0.f, wpart);

  int2 f2[KE_NUM], p2[KE_NUM];
  float2 pr2[KE_NUM];
  if (act) {
#pragma unroll
    for (int k = 0; k < KE_NUM; ++k) {
      f2[k] = ((const int2*)(ef + k * S_NUM))[tid];
      p2[k] = ((const int2*)(ep + k * S_NUM))[tid];
      pr2[k] = ((const float2*)(epr + k * S_NUM))[tid];
    }
  }
  obs[tid] = clampexp(xb[tid]);
  obs[tid + 1024] = clampexp(xb[tid + 1024]);
  if (tid + 2048 < P) obs[tid + 2048] = clampexp(xb[tid + 2048]);
  float xr0, xr1, xr2;
  {
    const float* r = xb + P;
    xr0 = r[tid];
    xr1 = r[tid + 1024];
    xr2 = (tid + 2048 < P) ? r[tid + 2048] : 0.f;
  }
  if (act) {
    cur[j] = ini.x;
    cur[j + 1] = ini.y;
  }
  __syncthreads();

  float logz = 0.f;
  for (int t = 0; t < T; ++t) {
    float nx0 = xr0, nx1 = xr1, nx2 = xr2;
    if (t + 2 < T) {
      const float* r = xb + (size_t)(t + 2) * P;
      nx0 = r[tid];
      nx1 = r[tid + 1024];
      nx2 = (tid + 2048 < P) ? r[tid + 2048] : 0.f;
    }
    float a0 = 0.f, a1 = 0.f;
    if (act) {
#pragma unroll
      for (int k = 0; k < KE_NUM; ++k) {
        a0 += cur[f2[k].x] * pr2[k].x * obs[p2[k].x];
        a1 += cur[f2[k].y] * pr2[k].y * obs[p2[k].y];
      }
    }
    float v = a0 + a1;
#pragma unroll
    for (int off = 32; off; off >>= 1) v += __shfl_xor(v, off, 64);
    if ((tid & 63) == 0) wpart[tid >> 6] = v;
    __syncthreads();
    float tot = 0.f;
#pragma unroll
    for (int w = 0; w < NWAVE; ++w) tot += wpart[w];
    if (t + 1 < T) {
      obs[tid] = clampexp(xr0);
      obs[tid + 1024] = clampexp(xr1);
      if (tid + 2048 < P) obs[tid + 2048] = clampexp(xr2);
    }
    xr0 = nx0;
    xr1 = nx1;
    xr2 = nx2;
    const float scale = tot * leakfac;
    const float inv = 1.f / scale, lt = LEAKY * tot;
    if (act) {
      cur[j] = fmaf(lt, ini.x, a0) * inv;
      cur[j + 1] = fmaf(lt, ini.y, a1) * inv;
    }
    logz += __logf(scale);
    __syncthreads();
  }
  __syncthreads();
  const float fin = reduce_1024(
      act ? (cur[j] * fin2.x + cur[j + 1] * fin2.y) : 0.f, wpart);
  if (tid == 0) *out_slot = logz + __logf(fin);
}

__global__ __launch_bounds__(NTH) void fb_kernel(
    const float* __restrict__ x, const int* __restrict__ den_from,
    const int* __restrict__ den_pdf, const float* __restrict__ den_prob,
    const float* __restrict__ den_init, const float* __restrict__ den_final,
    const int* __restrict__ num_from, const int* __restrict__ num_pdf,
    const float* __restrict__ num_prob, const float* __restrict__ num_init,
    const float* __restrict__ num_final, float* __restrict__ ws) {
  __shared__ float obsA[P];
  __shared__ float obsB[P];
  __shared__ float cur[S_DEN];
  __shared__ float ini_s[S_DEN];
  __shared__ float tmp[SB];
  __shared__ float wpart[NWAVE];
  float* outs = ws;
  float* parts = ws + 4096;
  const int blk = blockIdx.x;
  if (blk < NDEN_BLK) {
    const int b = blk / G_DEN, g = blk % G_DEN;
    run_den(x + (size_t)b * T * P, den_from, den_pdf, den_prob, den_init,
            den_final, b, g, outs, parts + (size_t)b * 4096, obsA, obsB, cur,
            ini_s, tmp, wpart);
  } else {
    const int b = blk - NDEN_BLK;
    run_num(x + (size_t)b * T * P, num_from + b * E_NUM, num_pdf + b * E_NUM,
            num_prob + b * E_NUM, num_init + b * S_NUM, num_final + b * S_NUM,
            outs + B + b, obsA, cur, wpart);
  }
}

// Sentinel fill: -1.0 has tag=1 (negative) -> wrong tag for t=0/t=1 (expect
// positive), so first-ever-run garbage can never alias fresh data. Idempotent
// across iterations (end-of-run buffers hold t=498/499 values, tag=1 too).
__global__ void init_parts(float* p) {
  st_f32(&p[blockIdx.x * NTH + threadIdx.x], -1.f);
}

__global__ void finish_kernel(const float* __restrict__ ws,
                              float* __restrict__ out) {
  const int tid = threadIdx.x;  // 64 threads: 32 den (+), 32 num (-)
  float v = ws[tid];
  v = (tid < B) ? v : -v;
#pragma unroll
  for (int off = 32; off; off >>= 1) v += __shfl_xor(v, off, 64);
  if (tid == 0) out[0] = v / (float)(B * T);  // objf = (den - num)/(B*T)
}

extern "C" void kernel_launch(void* const* d_in, const int* in_sizes, int n_in,
                              void* d_out, int out_size, void* d_ws,
                              size_t ws_size, hipStream_t stream) {
  const float* x = (const float*)d_in[0];
  const int* den_from = (const int*)d_in[1];
  // d_in[2] = den_to (structure exploited: to[e] == e % S_DEN)
  const int* den_pdf = (const int*)d_in[3];
  const float* den_prob = (const float*)d_in[4];
  const float* den_init = (const float*)d_in[5];
  const float* den_final = (const float*)d_in[6];
  const int* num_from = (const int*)d_in[7];
  // d_in[8] = num_to (structure exploited: to[e] == e % S_NUM)
  const int* num_pdf = (const int*)d_in[9];
  const float* num_prob = (const float*)d_in[10];
  const float* num_init = (const float*)d_in[11];
  const float* num_final = (const float*)d_in[12];
  float* ws = (float*)d_ws;
  float* out = (float*)d_out;

  init_parts<<<(B * 4096) / NTH, NTH, 0, stream>>>(ws + 4096);
  fb_kernel<<<NDEN_BLK + B, NTH, 0, stream>>>(
      x, den_from, den_pdf, den_prob, den_init, den_final, num_from, num_pdf,
      num_prob, num_init, num_final, ws);
  finish_kernel<<<1, 64, 0, stream>>>(ws, out);
}

// Round 2
// 1618.311 us; speedup vs baseline: 1.0453x; 1.0349x over previous
//
#include <hip/hip_runtime.h>

// ChainLoss (pychain leaky-HMM forward) on MI355X — round 11.
// Round-10 (self-validating sign-tag publishes, no flag/poll) was NEUTRAL vs
// round 9 (~1500us): sync cost is LLC latency + skew, already overlapped —
// protocol micro-opts exhausted. This round attacks the largest measured
// counter: SQ_LDS_BANK_CONFLICT = 1.005e8 (~1250 cy/block-step), produced by
// the two 10-read random LDS gathers (cur[from], obs[pdf]).
// CHANGE (prologue-only, zero steady-state cost): each gather thread sorts
// its 10 edges by the lane-staggered bank key ((from&31) - 3*lane) & 31.
// Slot k across 64 lanes then reads banks ~ (3*lane + const) mod 32; since
// gcd(3,32)=1 the offsets cover every bank exactly twice -> ~2-3-way access
// (2-way is free, m136) instead of ~6-way random. This fixes the CRITICAL-
// PATH gather (cur[from]); obs[pdf] reads stay random but sit in the hidden
// wait window. Sort = fully unrolled 45-compare bubble network (static reg
// indices, rule #20). FP: per-state edge-sum order changes (~1e-6 rel drift
// vs reference); cross-block determinism (consume/reduce order) unchanged.
// Retained from round 10: sign-tag freshness protocol (par=t&1 double buffer,
// tag=(t>>1)&1), G=5 split, 160 den + 32 num blocks, w-precompute in wait
// window, obs wave-specialization. Spill canary: WRITE_SIZE ~128 MB.

#define LEAKY 0.1f
#define AGENT __HIP_MEMORY_SCOPE_AGENT

constexpr int B = 32, T = 500, P = 3000;
constexpr int S_DEN = 2000;
constexpr int S_NUM = 100, E_NUM = 400;
constexpr int NTH = 1024;
constexpr int NWAVE = NTH / 64;
constexpr int G_DEN = 5;              // state-split factor
constexpr int SB = S_DEN / G_DEN;     // 400 states per den block
constexpr int KE = 20;                // incoming edges per state
constexpr int EPT = KE / 2;           // 10 edges per gather thread
constexpr int OBS_T0 = 800;           // threads >= OBS_T0 build obs
constexpr int OBS_N = NTH - OBS_T0;   // 224 obs threads
constexpr int OBS_IT = (P + OBS_N - 1) / OBS_N;  // 14
constexpr int KE_NUM = 4;
constexpr int NDEN_BLK = B * G_DEN;   // 160

// ws float layout:
//   [0,64)      per-seq logprob slots (32 den, 32 num)
//   [64,1088)   (unused)
//   [4096,..)   parts: seq b at 4096 + b*4096, slot par*2048 + state j
//               value = ((t>>1)&1) ? -alpha : +alpha  (sign = freshness tag)

__device__ __forceinline__ float clampexp(float x) {
  return __expf(fminf(fmaxf(x, -30.f), 30.f));
}
__device__ __forceinline__ void st_f32(float* p, float v) {
  __hip_atomic_store(p, v, __ATOMIC_RELAXED, AGENT);
}
__device__ __forceinline__ unsigned long long ld_u64(const float* p) {
  return __hip_atomic_load((const unsigned long long*)p, __ATOMIC_RELAXED,
                           AGENT);
}

// full-block reduce; caller guarantees wpart free (barrier since last use)
__device__ __forceinline__ float reduce_1024(float v, float* wpart) {
#pragma unroll
  for (int off = 32; off; off >>= 1) v += __shfl_xor(v, off, 64);
  if ((threadIdx.x & 63) == 0) wpart[threadIdx.x >> 6] = v;
  __syncthreads();
  float s = 0.f;
#pragma unroll
  for (int w = 0; w < NWAVE; ++w) s += wpart[w];
  return s;
}

__device__ void run_den(const float* __restrict__ xb,
                        const int* __restrict__ ef_g,
                        const int* __restrict__ ep_g,
                        const float* __restrict__ epr_g,
                        const float* __restrict__ einit,
                        const float* __restrict__ efinal, int b, int g,
                        float* __restrict__ outs, float* __restrict__ parts_b,
                        float* obsA, float* obsB, float* cur, float* ini_s,
                        float* tmp, float* wpart) {
  const int tid = threadIdx.x;
  const bool gat = tid < 2 * SB;          // 800 gather threads
  const bool own = tid < SB;              // owns state j
  const bool cons = tid < S_DEN / 2;      // consumes a float2 of parts
  const int jloc = own ? tid : (gat ? tid - SB : 0);
  const int khalf = (tid >= SB && gat) ? 1 : 0;
  const int j = g * SB + jloc;

  // init ini_s, cur, leakfac
  float lsum = 0.f;
  if (tid < S_DEN / 2) {
    const float2 iv = ((const float2*)einit)[tid];
    ((float2*)ini_s)[tid] = iv;
    ((float2*)cur)[tid] = iv;
    lsum = iv.x + iv.y;
  }
  __syncthreads();
  const float leakfac = 1.f + LEAKY * reduce_1024(lsum, wpart);

  // cache 10 edges of state j (half khalf): packed from|pdf<<16 + prob
  int efep[EPT];
  float epr[EPT], w[EPT];
  if (gat) {
#pragma unroll
    for (int k = 0; k < EPT; ++k) {
      const int e = j + (khalf * EPT + k) * S_DEN;
      efep[k] = ef_g[e] | (ep_g[e] << 16);
      epr[k] = epr_g[e];
    }
    // Bank-stagger sort (one-time): ascending by ((from&31) - 3*lane) & 31.
    // Slot k then hits bank ~ (3*lane + Qk) & 31 across the wave; 3*lane mod
    // 32 covers each bank exactly twice over 64 lanes -> ~2-3-way (near-free)
    // instead of ~6-way random on the critical-path cur gather.
    const int off = (3 * (tid & 63)) & 31;
#pragma unroll
    for (int i = 0; i < EPT - 1; ++i) {
#pragma unroll
      for (int k = 0; k < EPT - 1 - i; ++k) {
        const int ka = ((efep[k] & 31) - off) & 31;
        const int kb = ((efep[k + 1] & 31) - off) & 31;
        if (kb < ka) {
          const int te = efep[k]; efep[k] = efep[k + 1]; efep[k + 1] = te;
          const float tp = epr[k]; epr[k] = epr[k + 1]; epr[k + 1] = tp;
        }
      }
    }
  }

  // obs(t=0) by everyone (coalesced); obs-threads prefetch x row 1
  obsA[tid] = clampexp(xb[tid]);
  obsA[tid + 1024] = clampexp(xb[tid + 1024]);
  if (tid + 2048 < P) obsA[tid + 2048] = clampexp(xb[tid + 2048]);
  float xr[OBS_IT];
  if (tid >= OBS_T0) {
    const float* r = xb + P;
#pragma unroll
    for (int i = 0; i < OBS_IT; ++i) {
      const int p = tid - OBS_T0 + OBS_N * i;
      xr[i] = (p < P) ? r[p] : 0.f;
    }
  }
  __syncthreads();
  // w for t=0 from obsA
  if (gat) {
#pragma unroll
    for (int k = 0; k < EPT; ++k) w[k] = epr[k] * obsA[efep[k] >> 16];
  }

  float logz = 0.f;
  for (int t = 0; t < T; ++t) {
    const int par = t & 1;
    float* obs_n = par ? obsA : obsB;  // obs(t+1) buffer
    // phase G: gather threads do 10 fused reads; obs threads build obs_n
    float a = 0.f;
    if (gat) {
#pragma unroll
      for (int k = 0; k < EPT; ++k) a += cur[efep[k] & 0xffff] * w[k];
      if (!own) tmp[jloc] = a;  // second half stages its partial
    } else if (tid >= OBS_T0) {
      float nxr[OBS_IT];
      const int tn = (t + 2 < T) ? t + 2 : T - 1;
      const float* r = xb + (size_t)tn * P;
#pragma unroll
      for (int i = 0; i < OBS_IT; ++i) {   // issue x[t+2] loads early
        const int p = tid - OBS_T0 + OBS_N * i;
        nxr[i] = (p < P) ? r[p] : 0.f;
      }
      if (t + 1 < T) {
#pragma unroll
        for (int i = 0; i < OBS_IT; ++i) {
          const int p = tid - OBS_T0 + OBS_N * i;
          if (p < P) obs_n[p] = clampexp(xr[i]);
        }
      }
#pragma unroll
      for (int i = 0; i < OBS_IT; ++i) xr[i] = nxr[i];
    }
    __syncthreads();  // B1: tmp + obs_n ready (gather LDS reads for t done)
    // owners combine + publish own unnorm alpha, sign-tagged by (t>>1)&1.
    // No drain, no flag: each datum self-announces via its sign bit.
    const unsigned tag = ((unsigned)t >> 1) & 1u;
    if (own) {
      const float aa = a + tmp[tid];
      st_f32(parts_b + par * 2048 + j, tag ? -aa : aa);
    }
    // fire the consume load NOW — its LLC round trip overlaps w-precompute
    const float* myp = parts_b + par * 2048 + 2 * tid;
    unsigned long long u = 0;
    if (cons) u = ld_u64(myp);
    // w-precompute for t+1 — fills the wait window (obs_n ready since B1)
    if (gat && t + 1 < T) {
#pragma unroll
      for (int k = 0; k < EPT; ++k) w[k] = epr[k] * obs_n[efep[k] >> 16];
    }
    // per-thread spin: both lanes of own float2 must carry tag's sign
    if (cons) {
      while ((((unsigned)(u >> 31) & 1u) != tag) ||
             (((unsigned)(u >> 63) & 1u) != tag)) {
        __builtin_amdgcn_s_sleep(1);
        u = ld_u64(myp);
      }
    }
    union { unsigned long long q; float2 f; } cc;
    cc.q = u;
    const float2 v2 = make_float2(fabsf(cc.f.x), fabsf(cc.f.y));  // exact bits
    // tot via deterministic block reduce: same data, same order in all 5
    // blocks -> bit-identical scale everywhere (reduce's barrier = converge)
    const float tot = reduce_1024(v2.x + v2.y, wpart);
    const float scale = tot * leakfac;  // normalization choice telescopes out
    const float inv = 1.f / scale, lt = LEAKY * tot;
    if (cons) {
      const float2 i2 = ((const float2*)ini_s)[tid];
      ((float2*)cur)[tid] = make_float2(fmaf(lt, i2.x, v2.x) * inv,
                                        fmaf(lt, i2.y, v2.y) * inv);
    }
    logz += __logf(scale);
    __syncthreads();  // B4: cur ready for step t+1 (also fences wpart reuse)
  }

  float fv = 0.f;
  if (tid < S_DEN / 2) {
    const float2 f2 = ((const float2*)efinal)[tid];
    const float2 c2 = ((float2*)cur)[tid];
    fv = c2.x * f2.x + c2.y * f2.y;
  }
  const float fin = reduce_1024(fv, wpart);
  if (tid == 0 && g == 0) outs[b] = logz + __logf(fin);
}

__device__ void run_num(const float* __restrict__ xb, const int* __restrict__ ef,
                        const int* __restrict__ ep, const float* __restrict__ epr,
                        const float* __restrict__ einit,
                        const float* __restrict__ efinal,
                        float* __restrict__ out_slot, float* __restrict__ obs,
                        float* __restrict__ cur, float* __restrict__ wpart) {
  const int tid = threadIdx.x;
  const bool act = tid < S_NUM / 2;
  const int j = 2 * tid;
  float2 ini = make_float2(0.f, 0.f), fin2 = make_float2(0.f, 0.f);
  if (act) {
    ini = ((const float2*)einit)[tid];
    fin2 = ((const float2*)efinal)[tid];
  }
  __syncthreads();
  const float leakfac =
      1.f + LEAKY * reduce_1024(act ? ini.x + ini.y : 0.f, wpart);

  int2 f2[KE_NUM], p2[KE_NUM];
  float2 pr2[KE_NUM];
  if (act) {
#pragma unroll
    for (int k = 0; k < KE_NUM; ++k) {
      f2[k] = ((const int2*)(ef + k * S_NUM))[tid];
      p2[k] = ((const int2*)(ep + k * S_NUM))[tid];
      pr2[k] = ((const float2*)(epr + k * S_NUM))[tid];
    }
  }
  obs[tid] = clampexp(xb[tid]);
  obs[tid + 1024] = clampexp(xb[tid + 1024]);
  if (tid + 2048 < P) obs[tid + 2048] = clampexp(xb[tid + 2048]);
  float xr0, xr1, xr2;
  {
    const float* r = xb + P;
    xr0 = r[tid];
    xr1 = r[tid + 1024];
    xr2 = (tid + 2048 < P) ? r[tid + 2048] : 0.f;
  }
  if (act) {
    cur[j] = ini.x;
    cur[j + 1] = ini.y;
  }
  __syncthreads();

  float logz = 0.f;
  for (int t = 0; t < T; ++t) {
    float nx0 = xr0, nx1 = xr1, nx2 = xr2;
    if (t + 2 < T) {
      const float* r = xb + (size_t)(t + 2) * P;
      nx0 = r[tid];
      nx1 = r[tid + 1024];
      nx2 = (tid + 2048 < P) ? r[tid + 2048] : 0.f;
    }
    float a0 = 0.f, a1 = 0.f;
    if (act) {
#pragma unroll
      for (int k = 0; k < KE_NUM; ++k) {
        a0 += cur[f2[k].x] * pr2[k].x * obs[p2[k].x];
        a1 += cur[f2[k].y] * pr2[k].y * obs[p2[k].y];
      }
    }
    float v = a0 + a1;
#pragma unroll
    for (int off = 32; off; off >>= 1) v += __shfl_xor(v, off, 64);
    if ((tid & 63) == 0) wpart[tid >> 6] = v;
    __syncthreads();
    float tot = 0.f;
#pragma unroll
    for (int w = 0; w < NWAVE; ++w) tot += wpart[w];
    if (t + 1 < T) {
      obs[tid] = clampexp(xr0);
      obs[tid + 1024] = clampexp(xr1);
      if (tid + 2048 < P) obs[tid + 2048] = clampexp(xr2);
    }
    xr0 = nx0;
    xr1 = nx1;
    xr2 = nx2;
    const float scale = tot * leakfac;
    const float inv = 1.f / scale, lt = LEAKY * tot;
    if (act) {
      cur[j] = fmaf(lt, ini.x, a0) * inv;
      cur[j + 1] = fmaf(lt, ini.y, a1) * inv;
    }
    logz += __logf(scale);
    __syncthreads();
  }
  __syncthreads();
  const float fin = reduce_1024(
      act ? (cur[j] * fin2.x + cur[j + 1] * fin2.y) : 0.f, wpart);
  if (tid == 0) *out_slot = logz + __logf(fin);
}

__global__ __launch_bounds__(NTH) void fb_kernel(
    const float* __restrict__ x, const int* __restrict__ den_from,
    const int* __restrict__ den_pdf, const float* __restrict__ den_prob,
    const float* __restrict__ den_init, const float* __restrict__ den_final,
    const int* __restrict__ num_from, const int* __restrict__ num_pdf,
    const float* __restrict__ num_prob, const float* __restrict__ num_init,
    const float* __restrict__ num_final, float* __restrict__ ws) {
  __shared__ float obsA[P];
  __shared__ float obsB[P];
  __shared__ float cur[S_DEN];
  __shared__ float ini_s[S_DEN];
  __shared__ float tmp[SB];
  __shared__ float wpart[NWAVE];
  float* outs = ws;
  float* parts = ws + 4096;
  const int blk = blockIdx.x;
  if (blk < NDEN_BLK) {
    const int b = blk / G_DEN, g = blk % G_DEN;
    run_den(x + (size_t)b * T * P, den_from, den_pdf, den_prob, den_init,
            den_final, b, g, outs, parts + (size_t)b * 4096, obsA, obsB, cur,
            ini_s, tmp, wpart);
  } else {
    const int b = blk - NDEN_BLK;
    run_num(x + (size_t)b * T * P, num_from + b * E_NUM, num_pdf + b * E_NUM,
            num_prob + b * E_NUM, num_init + b * S_NUM, num_final + b * S_NUM,
            outs + B + b, obsA, cur, wpart);
  }
}

// Sentinel fill: -1.0 has tag=1 (negative) -> wrong tag for t=0/t=1 (expect
// positive), so first-ever-run garbage can never alias fresh data. Idempotent
// across iterations (end-of-run buffers hold t=498/499 values, tag=1 too).
__global__ void init_parts(float* p) {
  st_f32(&p[blockIdx.x * NTH + threadIdx.x], -1.f);
}

__global__ void finish_kernel(const float* __restrict__ ws,
                              float* __restrict__ out) {
  const int tid = threadIdx.x;  // 64 threads: 32 den (+), 32 num (-)
  float v = ws[tid];
  v = (tid < B) ? v : -v;
#pragma unroll
  for (int off = 32; off; off >>= 1) v += __shfl_xor(v, off, 64);
  if (tid == 0) out[0] = v / (float)(B * T);  // objf = (den - num)/(B*T)
}

extern "C" void kernel_launch(void* const* d_in, const int* in_sizes, int n_in,
                              void* d_out, int out_size, void* d_ws,
                              size_t ws_size, hipStream_t stream) {
  const float* x = (const float*)d_in[0];
  const int* den_from = (const int*)d_in[1];
  // d_in[2] = den_to (structure exploited: to[e] == e % S_DEN)
  const int* den_pdf = (const int*)d_in[3];
  const float* den_prob = (const float*)d_in[4];
  const float* den_init = (const float*)d_in[5];
  const float* den_final = (const float*)d_in[6];
  const int* num_from = (const int*)d_in[7];
  // d_in[8] = num_to (structure exploited: to[e] == e % S_NUM)
  const int* num_pdf = (const int*)d_in[9];
  const float* num_prob = (const float*)d_in[10];
  const float* num_init = (const float*)d_in[11];
  const float* num_final = (const float*)d_in[12];
  float* ws = (float*)d_ws;
  float* out = (float*)d_out;

  init_parts<<<(B * 4096) / NTH, NTH, 0, stream>>>(ws + 4096);
  fb_kernel<<<NDEN_BLK + B, NTH, 0, stream>>>(
      x, den_from, den_pdf, den_prob, den_init, den_final, num_from, num_pdf,
      num_prob, num_init, num_final, ws);
  finish_kernel<<<1, 64, 0, stream>>>(ws, out);
}

// Round 4
// 1334.956 us; speedup vs baseline: 1.2672x; 1.2123x over previous
//
#include <hip/hip_runtime.h>

// ChainLoss (pychain leaky-HMM forward) on MI355X — round 12 (resubmit;
// round-3 bench was a GPUAcquisitionTimeout, kernel never ran).
// Round-11 post-mortem: bank-stagger sort left conflicts ~unchanged (-2.7%)
// but time -4% — conflicts are NOT the lever. This round shortens the serial
// per-step chain (consume -> gather -> combine -> publish -> RT -> spin ->
// reduce -> cur-build) by restructuring, leaving LDS gather volume as-is:
//  1. WAVE-PAIR COMBINE: state halves on adjacent lanes of one wave; combine
//     via __shfl_xor(a,1) and publish IMMEDIATELY after the wave's own
//     gather — no tmp, no B1 in the publish path, immune to obs-thread skew.
//  2. RAW-GATHER with deferred leak/inv: consumers write RAW published bytes
//     to LDS right after spin (no reduce needed first). Gather computes
//     a_raw = sum raw[from]*w and iniw = sum c_k*obs[pdf] where c_k =
//     ini[from]*epr (static, prologue) — iniw fuses into the w-precompute
//     (same obs read, +1 FMA, ZERO extra LDS traffic). Final per state:
//     aa = inv*(a_raw + lt*iniw), scalars applied at the end. The reduce
//     tail (16 broadcast reads) moves to the next iteration top where it
//     interleaves with the gather's independent LDS loads.
//  3. Barriers 3 -> 2 per step (B1; merged end barrier for craw+wpart).
// Tag protocol re-indexed (iter t publishes parts(t+1)): per-parity sentinel
// (+1.0 for par0, -1.0 for par1) so first-use tags mismatch. Determinism:
// all 5 blocks consume identical bytes + identical wpart-sum order ->
// bit-identical tot/scale. VGPR ~80 < 128 (16-wave launch limit) — canary:
// kernel must still launch, WRITE_SIZE ~125 MB (no spill).
// Retained: G=5 split, sign-tag freshness, bank-stagger sort, obs wave
// specialization with double buffer, consume-load fired before w-precompute.

#define LEAKY 0.1f
#define AGENT __HIP_MEMORY_SCOPE_AGENT

constexpr int B = 32, T = 500, P = 3000;
constexpr int S_DEN = 2000;
constexpr int S_NUM = 100, E_NUM = 400;
constexpr int NTH = 1024;
constexpr int NWAVE = NTH / 64;
constexpr int G_DEN = 5;              // state-split factor
constexpr int SB = S_DEN / G_DEN;     // 400 states per den block
constexpr int KE = 20;                // incoming edges per state
constexpr int EPT = KE / 2;           // 10 edges per gather thread
constexpr int OBS_T0 = 800;           // threads >= OBS_T0 build obs
constexpr int OBS_N = NTH - OBS_T0;   // 224 obs threads
constexpr int OBS_IT = (P + OBS_N - 1) / OBS_N;  // 14
constexpr int KE_NUM = 4;
constexpr int NDEN_BLK = B * G_DEN;   // 160

// ws float layout:
//   [0,64)      per-seq logprob slots (32 den, 32 num)
//   [4096,..)   parts: seq b at 4096 + b*4096, slot par*2048 + state j
//               iter t publishes parts(t+1) at par=(t+1)&1 with sign tag
//               ((t+1)>>1)&1 (0 -> +alpha, 1 -> -alpha)

__device__ __forceinline__ float clampexp(float x) {
  return __expf(fminf(fmaxf(x, -30.f), 30.f));
}
__device__ __forceinline__ void st_f32(float* p, float v) {
  __hip_atomic_store(p, v, __ATOMIC_RELAXED, AGENT);
}
__device__ __forceinline__ unsigned long long ld_u64(const float* p) {
  return __hip_atomic_load((const unsigned long long*)p, __ATOMIC_RELAXED,
                           AGENT);
}

// full-block reduce; caller guarantees wpart free (barrier since last use)
__device__ __forceinline__ float reduce_1024(float v, float* wpart) {
#pragma unroll
  for (int off = 32; off; off >>= 1) v += __shfl_xor(v, off, 64);
  if ((threadIdx.x & 63) == 0) wpart[threadIdx.x >> 6] = v;
  __syncthreads();
  float s = 0.f;
#pragma unroll
  for (int w = 0; w < NWAVE; ++w) s += wpart[w];
  return s;
}

__device__ void run_den(const float* __restrict__ xb,
                        const int* __restrict__ ef_g,
                        const int* __restrict__ ep_g,
                        const float* __restrict__ epr_g,
                        const float* __restrict__ einit,
                        const float* __restrict__ efinal, int b, int g,
                        float* __restrict__ outs, float* __restrict__ parts_b,
                        float* obsA, float* obsB, float* cur, float* ini_s,
                        float* wpart) {
  const int tid = threadIdx.x;
  const int lane = tid & 63;
  const bool gat = tid < 2 * SB;          // 800 gather threads (12.5 waves)
  const bool cons = tid < S_DEN / 2;      // 1000 consumer threads
  // wave-pair mapping: lanes (2m, 2m+1) of a wave own halves 0/1 of a state
  const int jloc = (tid >> 6) * 32 + (lane >> 1);
  const int half = lane & 1;
  const int j = g * SB + jloc;

  // init ini_s + leakfac
  float lsum = 0.f;
  if (cons) {
    const float2 iv = ((const float2*)einit)[tid];
    ((float2*)ini_s)[tid] = iv;
    lsum = iv.x + iv.y;
  }
  __syncthreads();
  const float leakfac = 1.f + LEAKY * reduce_1024(lsum, wpart);

  // cache 10 edges of (state j, half): packed from|pdf<<16, prob, c=ini*prob
  int efep[EPT];
  float epr[EPT], w[EPT], c[EPT];
  if (gat) {
#pragma unroll
    for (int k = 0; k < EPT; ++k) {
      const int e = j + (half * EPT + k) * S_DEN;
      efep[k] = ef_g[e] | (ep_g[e] << 16);
      epr[k] = epr_g[e];
    }
    // bank-stagger sort (kept from round 11; one-time)
    const int off = (3 * lane) & 31;
#pragma unroll
    for (int i = 0; i < EPT - 1; ++i) {
#pragma unroll
      for (int k = 0; k < EPT - 1 - i; ++k) {
        const int ka = ((efep[k] & 31) - off) & 31;
        const int kb = ((efep[k + 1] & 31) - off) & 31;
        if (kb < ka) {
          const int te = efep[k]; efep[k] = efep[k + 1]; efep[k + 1] = te;
          const float tp = epr[k]; epr[k] = epr[k + 1]; epr[k + 1] = tp;
        }
      }
    }
#pragma unroll
    for (int k = 0; k < EPT; ++k) c[k] = ini_s[efep[k] & 0xffff] * epr[k];
  }

  // obs(t=0) by everyone (coalesced); obs-threads prefetch x row 1
  obsA[tid] = clampexp(xb[tid]);
  obsA[tid + 1024] = clampexp(xb[tid + 1024]);
  if (tid + 2048 < P) obsA[tid + 2048] = clampexp(xb[tid + 2048]);
  float xr[OBS_IT];
  if (tid >= OBS_T0) {
    const float* r = xb + P;
#pragma unroll
    for (int i = 0; i < OBS_IT; ++i) {
      const int p = tid - OBS_T0 + OBS_N * i;
      xr[i] = (p < P) ? r[p] : 0.f;
    }
  }
  __syncthreads();
  // w + iniw for t=0 from obsA
  float iniw = 0.f;
  if (gat) {
#pragma unroll
    for (int k = 0; k < EPT; ++k) {
      const float o = obsA[efep[k] >> 16];
      w[k] = epr[k] * o;
      iniw += c[k] * o;
    }
  }

  float logz = 0.f;
  float lt = 0.f, inv = 0.f;
  for (int t = 0; t < T; ++t) {
    float* obs_n = (t & 1) ? obsA : obsB;  // obs(t+1) buffer
    // top: gather on RAW craw(t) (in `cur`) + reduce tail of tot(t) —
    // independent streams; the compiler interleaves the LDS loads with the
    // broadcast wpart reads + log. Skipped at t==0 (cur(0)=ini handled via
    // the exact identity aa(1) = iniw).
    float a_raw = 0.f;
    if (t) {
      if (gat) {
#pragma unroll
        for (int k = 0; k < EPT; ++k) a_raw += cur[efep[k] & 0xffff] * w[k];
      }
      float s = 0.f;
#pragma unroll
      for (int wv = 0; wv < NWAVE; ++wv) s += wpart[wv];
      const float scale = s * leakfac;
      lt = LEAKY * s;
      inv = 1.f / scale;
      logz += __logf(scale);
    }
    // wave-pair combine + IMMEDIATE publish of parts(t+1) (no barrier dep)
    const int parn = (t + 1) & 1;
    const unsigned tagn = ((unsigned)(t + 1) >> 1) & 1u;
    if (gat) {
      const float ar = a_raw + __shfl_xor(a_raw, 1, 64);
      const float iw = iniw + __shfl_xor(iniw, 1, 64);
      if (!half) {
        const float aa = t ? inv * fmaf(lt, iw, ar) : iw;
        st_f32(parts_b + parn * 2048 + j, tagn ? -aa : aa);
      }
    } else if (tid >= OBS_T0) {
      float nxr[OBS_IT];
      const int tn = (t + 2 < T) ? t + 2 : T - 1;
      const float* r = xb + (size_t)tn * P;
#pragma unroll
      for (int i = 0; i < OBS_IT; ++i) {   // issue x[t+2] loads early
        const int p = tid - OBS_T0 + OBS_N * i;
        nxr[i] = (p < P) ? r[p] : 0.f;
      }
      if (t + 1 < T) {
#pragma unroll
        for (int i = 0; i < OBS_IT; ++i) {
          const int p = tid - OBS_T0 + OBS_N * i;
          if (p < P) obs_n[p] = clampexp(xr[i]);
        }
      }
#pragma unroll
      for (int i = 0; i < OBS_IT; ++i) xr[i] = nxr[i];
    }
    __syncthreads();  // B1: obs_n ready; top reads of cur/wpart all complete
    // fire consume load NOW — LLC round trip overlaps w/iniw-precompute
    const float* myp = parts_b + parn * 2048 + 2 * tid;
    unsigned long long u = 0;
    if (cons) u = ld_u64(myp);
    // w + iniw precompute for t+1 (obs_n ready since B1; zero extra reads)
    if (gat && t + 1 < T) {
      iniw = 0.f;
#pragma unroll
      for (int k = 0; k < EPT; ++k) {
        const float o = obs_n[efep[k] >> 16];
        w[k] = epr[k] * o;
        iniw += c[k] * o;
      }
    }
    // per-thread spin: both lanes of own float2 must carry tagn's sign
    if (cons) {
      while ((((unsigned)(u >> 31) & 1u) != tagn) ||
             (((unsigned)(u >> 63) & 1u) != tagn)) {
        __builtin_amdgcn_s_sleep(1);
        u = ld_u64(myp);
      }
    }
    union { unsigned long long q; float2 f; } cc;
    cc.q = u;
    const float2 v2 = make_float2(fabsf(cc.f.x), fabsf(cc.f.y));  // exact bits
    // write RAW craw(t+1) + wpart partials; single end barrier
    float pv = cons ? (v2.x + v2.y) : 0.f;
#pragma unroll
    for (int off2 = 32; off2; off2 >>= 1) pv += __shfl_xor(pv, off2, 64);
    if (lane == 0) wpart[tid >> 6] = pv;
    if (cons) ((float2*)cur)[tid] = v2;
    __syncthreads();  // Bend: craw(t+1) + wpart(t+1) ready
  }

  // epilogue: tot(T) + final dot with deferred leak/inv applied explicitly
  float s = 0.f;
#pragma unroll
  for (int wv = 0; wv < NWAVE; ++wv) s += wpart[wv];
  const float scaleT = s * leakfac;
  logz += __logf(scaleT);
  const float ltT = LEAKY * s, invT = 1.f / scaleT;
  float fv = 0.f;
  if (cons) {
    const float2 f2 = ((const float2*)efinal)[tid];
    const float2 i2 = ((const float2*)ini_s)[tid];
    const float2 c2 = ((const float2*)cur)[tid];
    fv = (fmaf(ltT, i2.x, c2.x) * invT) * f2.x +
         (fmaf(ltT, i2.y, c2.y) * invT) * f2.y;
  }
  __syncthreads();  // wpart reads above complete before reduce reuses it
  const float fin = reduce_1024(fv, wpart);
  if (tid == 0 && g == 0) outs[b] = logz + __logf(fin);
}

__device__ void run_num(const float* __restrict__ xb, const int* __restrict__ ef,
                        const int* __restrict__ ep, const float* __restrict__ epr,
                        const float* __restrict__ einit,
                        const float* __restrict__ efinal,
                        float* __restrict__ out_slot, float* __restrict__ obs,
                        float* __restrict__ cur, float* __restrict__ wpart) {
  const int tid = threadIdx.x;
  const bool act = tid < S_NUM / 2;
  const int j = 2 * tid;
  float2 ini = make_float2(0.f, 0.f), fin2 = make_float2(0.f, 0.f);
  if (act) {
    ini = ((const float2*)einit)[tid];
    fin2 = ((const float2*)efinal)[tid];
  }
  __syncthreads();
  const float leakfac =
      1.f + LEAKY * reduce_1024(act ? ini.x + ini.y : 0.f, wpart);

  int2 f2[KE_NUM], p2[KE_NUM];
  float2 pr2[KE_NUM];
  if (act) {
#pragma unroll
    for (int k = 0; k < KE_NUM; ++k) {
      f2[k] = ((const int2*)(ef + k * S_NUM))[tid];
      p2[k] = ((const int2*)(ep + k * S_NUM))[tid];
      pr2[k] = ((const float2*)(epr + k * S_NUM))[tid];
    }
  }
  obs[tid] = clampexp(xb[tid]);
  obs[tid + 1024] = clampexp(xb[tid + 1024]);
  if (tid + 2048 < P) obs[tid + 2048] = clampexp(xb[tid + 2048]);
  float xr0, xr1, xr2;
  {
    const float* r = xb + P;
    xr0 = r[tid];
    xr1 = r[tid + 1024];
    xr2 = (tid + 2048 < P) ? r[tid + 2048] : 0.f;
  }
  if (act) {
    cur[j] = ini.x;
    cur[j + 1] = ini.y;
  }
  __syncthreads();

  float logz = 0.f;
  for (int t = 0; t < T; ++t) {
    float nx0 = xr0, nx1 = xr1, nx2 = xr2;
    if (t + 2 < T) {
      const float* r = xb + (size_t)(t + 2) * P;
      nx0 = r[tid];
      nx1 = r[tid + 1024];
      nx2 = (tid + 2048 < P) ? r[tid + 2048] : 0.f;
    }
    float a0 = 0.f, a1 = 0.f;
    if (act) {
#pragma unroll
      for (int k = 0; k < KE_NUM; ++k) {
        a0 += cur[f2[k].x] * pr2[k].x * obs[p2[k].x];
        a1 += cur[f2[k].y] * pr2[k].y * obs[p2[k].y];
      }
    }
    float v = a0 + a1;
#pragma unroll
    for (int off = 32; off; off >>= 1) v += __shfl_xor(v, off, 64);
    if ((tid & 63) == 0) wpart[tid >> 6] = v;
    __syncthreads();
    float tot = 0.f;
#pragma unroll
    for (int w = 0; w < NWAVE; ++w) tot += wpart[w];
    if (t + 1 < T) {
      obs[tid] = clampexp(xr0);
      obs[tid + 1024] = clampexp(xr1);
      if (tid + 2048 < P) obs[tid + 2048] = clampexp(xr2);
    }
    xr0 = nx0;
    xr1 = nx1;
    xr2 = nx2;
    const float scale = tot * leakfac;
    const float inv = 1.f / scale, lt = LEAKY * tot;
    if (act) {
      cur[j] = fmaf(lt, ini.x, a0) * inv;
      cur[j + 1] = fmaf(lt, ini.y, a1) * inv;
    }
    logz += __logf(scale);
    __syncthreads();
  }
  __syncthreads();
  const float fin = reduce_1024(
      act ? (cur[j] * fin2.x + cur[j + 1] * fin2.y) : 0.f, wpart);
  if (tid == 0) *out_slot = logz + __logf(fin);
}

__global__ __launch_bounds__(NTH) void fb_kernel(
    const float* __restrict__ x, const int* __restrict__ den_from,
    const int* __restrict__ den_pdf, const float* __restrict__ den_prob,
    const float* __restrict__ den_init, const float* __restrict__ den_final,
    const int* __restrict__ num_from, const int* __restrict__ num_pdf,
    const float* __restrict__ num_prob, const float* __restrict__ num_init,
    const float* __restrict__ num_final, float* __restrict__ ws) {
  __shared__ float obsA[P];
  __shared__ float obsB[P];
  __shared__ float cur[S_DEN];
  __shared__ float ini_s[S_DEN];
  __shared__ float wpart[NWAVE];
  float* outs = ws;
  float* parts = ws + 4096;
  const int blk = blockIdx.x;
  if (blk < NDEN_BLK) {
    const int b = blk / G_DEN, g = blk % G_DEN;
    run_den(x + (size_t)b * T * P, den_from, den_pdf, den_prob, den_init,
            den_final, b, g, outs, parts + (size_t)b * 4096, obsA, obsB, cur,
            ini_s, wpart);
  } else {
    const int b = blk - NDEN_BLK;
    run_num(x + (size_t)b * T * P, num_from + b * E_NUM, num_pdf + b * E_NUM,
            num_prob + b * E_NUM, num_init + b * S_NUM, num_final + b * S_NUM,
            outs + B + b, obsA, cur, wpart);
  }
}

// Per-parity sentinel: first publish into par1 is iter t=0 (tag 0, positive)
// -> sentinel -1.0; first publish into par0 is iter t=1 (tag 1, negative)
// -> sentinel +1.0. Re-run each launch (idempotent across iterations).
__global__ void init_parts(float* p) {
  const int i = blockIdx.x * NTH + threadIdx.x;
  st_f32(&p[i], ((i >> 11) & 1) ? -1.f : 1.f);
}

__global__ void finish_kernel(const float* __restrict__ ws,
                              float* __restrict__ out) {
  const int tid = threadIdx.x;  // 64 threads: 32 den (+), 32 num (-)
  float v = ws[tid];
  v = (tid < B) ? v : -v;
#pragma unroll
  for (int off = 32; off; off >>= 1) v += __shfl_xor(v, off, 64);
  if (tid == 0) out[0] = v / (float)(B * T);  // objf = (den - num)/(B*T)
}

extern "C" void kernel_launch(void* const* d_in, const int* in_sizes, int n_in,
                              void* d_out, int out_size, void* d_ws,
                              size_t ws_size, hipStream_t stream) {
  const float* x = (const float*)d_in[0];
  const int* den_from = (const int*)d_in[1];
  // d_in[2] = den_to (structure exploited: to[e] == e % S_DEN)
  const int* den_pdf = (const int*)d_in[3];
  const float* den_prob = (const float*)d_in[4];
  const float* den_init = (const float*)d_in[5];
  const float* den_final = (const float*)d_in[6];
  const int* num_from = (const int*)d_in[7];
  // d_in[8] = num_to (structure exploited: to[e] == e % S_NUM)
  const int* num_pdf = (const int*)d_in[9];
  const float* num_prob = (const float*)d_in[10];
  const float* num_init = (const float*)d_in[11];
  const float* num_final = (const float*)d_in[12];
  float* ws = (float*)d_ws;
  float* out = (float*)d_out;

  init_parts<<<(B * 4096) / NTH, NTH, 0, stream>>>(ws + 4096);
  fb_kernel<<<NDEN_BLK + B, NTH, 0, stream>>>(
      x, den_from, den_pdf, den_prob, den_init, den_final, num_from, num_pdf,
      num_prob, num_init, num_final, ws);
  finish_kernel<<<1, 64, 0, stream>>>(ws, out);
}